// Round 1
// baseline (726.935 us; speedup 1.0000x reference)
//
#include <hip/hip_runtime.h>
#include <hip/hip_bf16.h>
#include <math.h>

// BahdanauAttention: B=32, S=2048, H=1024, fp32 in/out.
// R6: eliminate the keys fp32->bf16 conversion pass (384 MB of HBM traffic).
// scores GEMM reads fp32 keys directly: A-operand reg-staged with
// v_cvt_pk_bf16_f32 (RNE, bit-identical to previous bf16_rne path) into the
// same chunk_f-swizzled LDS layout; next K-step's A loads issued before the
// compute phase (T14 async-split) so HBM latency hides under MFMA.
// B-operand (Ua, 2 MB) keeps the proven GLDS width-16 path.
// prep is now tiny: qproj (512 blocks, launched first) + Ua convert (32).

#define B_ 32
#define S_ 2048
#define H_ 1024
#define M_ (B_ * S_)

#define QP_BLOCKS 512      // qproj
#define UA_BLOCKS 32       // Ua fp32->bf16

typedef __bf16 bf16x8 __attribute__((ext_vector_type(8)));
typedef float floatx4 __attribute__((ext_vector_type(4)));

__device__ inline unsigned bf16_rne(float f) {
  unsigned u = __builtin_bit_cast(unsigned, f);
  return (u + 0x7fffu + ((u >> 16) & 1u)) >> 16;
}
__device__ inline unsigned pk2(float x, float y) {
  return bf16_rne(x) | (bf16_rne(y) << 16);
}
// HW packed f32->bf16 (RNE) — 1 op per 2 elements.
__device__ inline unsigned cvtpk(float x, float y) {
  unsigned r;
  asm("v_cvt_pk_bf16_f32 %0, %1, %2" : "=v"(r) : "v"(x), "v"(y));
  return r;
}

// tanh via v_exp_f32 + v_rcp_f32 (~7 ops); rel err ~1e-6, << bf16 GEMM noise.
__device__ inline float fast_tanh(float x) {
  const float xc = fminf(fmaxf(x, -8.f), 8.f);
  const float e = __expf(2.f * xc);
  return (e - 1.f) * __builtin_amdgcn_rcpf(e + 1.f);
}

#define GLDS(g, l)                                                    \
  __builtin_amdgcn_global_load_lds(                                   \
      (const __attribute__((address_space(1))) void*)(g),             \
      (__attribute__((address_space(3))) void*)(l), 16, 0, 0)

__device__ inline uint4 conv8(const float4* s2) {
  const float4 a = s2[0], b = s2[1];
  uint4 o;
  o.x = pk2(a.x, a.y); o.y = pk2(a.z, a.w);
  o.z = pk2(b.x, b.y); o.w = pk2(b.z, b.w);
  return o;
}

// ---------------- prep: qproj | Ua->bf16 (keys conversion REMOVED) ----------------
__global__ __launch_bounds__(256) void prep_kernel(
    const float* __restrict__ Ua_w, const float* __restrict__ query,
    const float* __restrict__ Wa_w, const float* __restrict__ Wa_b,
    const float* __restrict__ Ua_b, unsigned short* __restrict__ ubf,
    float* __restrict__ qp, int do_ua) {
  const int blk = blockIdx.x;
  const int tid = threadIdx.x;
  if (blk < QP_BLOCKS) {
    // qproj: block = (b, 64-o slice). Wa read 64 rows/block coalesced; query in LDS.
    const int b = blk >> 4;
    const int os = (blk & 15) * 64;
    const int lane = tid & 63;
    const int w = tid >> 6;
    __shared__ float qsh[H_];
    *(float4*)&qsh[tid * 4] = *(const float4*)(query + (size_t)b * H_ + tid * 4);
    __syncthreads();
    for (int t = 0; t < 16; ++t) {
      const int o = os + w * 16 + t;
      const float* wr = Wa_w + (size_t)o * H_;
      float p = 0.f;
#pragma unroll
      for (int j = 0; j < 16; ++j) p += wr[lane + 64 * j] * qsh[lane + 64 * j];
#pragma unroll
      for (int m = 32; m; m >>= 1) p += __shfl_xor(p, m);
      if (lane == 0) qp[b * H_ + o] = p + Wa_b[o] + Ua_b[o];
    }
  } else {
    if (!do_ua) return;
    const int tg = (blk - QP_BLOCKS) * 256 + tid;  // [0, 8192)
#pragma unroll
    for (int c = 0; c < 16; ++c) {
      const size_t idx = (size_t)c * 8192 + tg;  // < 131072
      ((uint4*)ubf)[idx] = conv8((const float4*)Ua_w + idx * 2);
    }
  }
}

// XCD swizzle: 8 colblocks of a rowblock share idx%8 -> same XCD L2 keys tile.
__device__ inline void swizzle_rc(int idx, int& rb, int& cb) {
  cb = (idx >> 3) & 7;
  rb = (idx & 7) | ((idx >> 6) << 3);
}
__device__ inline int chunk_f(int r) { return (r & 3) ^ ((r >> 2) & 3); }

// ---------------- scores: fp32-A reg-staged + bf16 GEMM + tanh/Va epilogue ----------------
__global__ __launch_bounds__(256) void scores_af32_kernel(
    const float* __restrict__ keys, const unsigned short* __restrict__ ubf,
    const float* __restrict__ qp, const float* __restrict__ Va_w,
    float* __restrict__ sp) {  // sp[cb][M_]
  const int tid = threadIdx.x;
  int rb, cb;
  swizzle_rc(blockIdx.x, rb, cb);
  const int row0 = rb * 128, c0 = cb * 128;
  const int bq = row0 >> 11;
  const int lane = tid & 63;
  const int w = tid >> 6;
  const int wm = w >> 1, wn = w & 1;
  const int q4 = lane >> 4, n16 = lane & 15;

  __shared__ __align__(16) unsigned short Asm[128][32];
  __shared__ __align__(16) unsigned short Bsm[128][32];
  __shared__ float red[2][128];

  floatx4 acc[4][4];
#pragma unroll
  for (int i = 0; i < 4; ++i)
#pragma unroll
    for (int j = 0; j < 4; ++j) acc[i][j] = {0.f, 0.f, 0.f, 0.f};

  // B staging via GLDS (pre-swizzled global source), unchanged from R5.
  const int r0a = w * 32;
  const int lr = lane >> 2;
  const int lc = ((lane & 3) ^ chunk_f(lr)) * 8;
  const unsigned short* gB0 = ubf + (size_t)(c0 + r0a + lr) * H_ + lc;
  const unsigned short* gB1 = ubf + (size_t)(c0 + r0a + 16 + lr) * H_ + lc;
  unsigned short* lB0 = &Bsm[r0a][0];
  unsigned short* lB1 = &Bsm[r0a + 16][0];

  // A staging: thread t owns row ar = t>>1, global chunks ac0, ac0+1 (8 bf16 each).
  // Write global chunk c at LDS chunk c ^ chunk_f(row) — same involution the
  // ds_read side already uses, so the compute phase is unchanged.
  const int ar = tid >> 1;
  const int ac0 = (tid & 1) * 2;
  const float* gA = keys + (size_t)(row0 + ar) * H_ + ac0 * 8;
  unsigned short* lA0 = &Asm[ar][((ac0 ^ chunk_f(ar)) & 3) * 8];
  unsigned short* lA1 = &Asm[ar][(((ac0 + 1) ^ chunk_f(ar)) & 3) * 8];

  const int fn = chunk_f(n16);

  // Prologue: issue first A loads (fp32, 64B/thread).
  float4 a0 = *(const float4*)(gA + 0);
  float4 a1 = *(const float4*)(gA + 4);
  float4 a2 = *(const float4*)(gA + 8);
  float4 a3 = *(const float4*)(gA + 12);

  for (int kt = 0; kt < 32; ++kt) {
    const int k0 = kt * 32;
    __syncthreads();
    GLDS(gB0 + k0, lB0);
    GLDS(gB1 + k0, lB1);
    uint4 u0, u1;
    u0.x = cvtpk(a0.x, a0.y); u0.y = cvtpk(a0.z, a0.w);
    u0.z = cvtpk(a1.x, a1.y); u0.w = cvtpk(a1.z, a1.w);
    u1.x = cvtpk(a2.x, a2.y); u1.y = cvtpk(a2.z, a2.w);
    u1.z = cvtpk(a3.x, a3.y); u1.w = cvtpk(a3.z, a3.w);
    *(uint4*)lA0 = u0;
    *(uint4*)lA1 = u1;
    // T14 split: issue next K-step's A loads now; latency hides under MFMA.
    const int kn = ((kt + 1) & 31) * 32;  // wraps to 0 on last iter (unused, in-bounds)
    a0 = *(const float4*)(gA + kn + 0);
    a1 = *(const float4*)(gA + kn + 4);
    a2 = *(const float4*)(gA + kn + 8);
    a3 = *(const float4*)(gA + kn + 12);
    __syncthreads();
    bf16x8 af[4], bfr[4];
#pragma unroll
    for (int i = 0; i < 4; ++i)
      af[i] = *(const bf16x8*)&Asm[wm * 64 + i * 16 + n16][(q4 ^ fn) * 8];
#pragma unroll
    for (int j = 0; j < 4; ++j)
      bfr[j] = *(const bf16x8*)&Bsm[wn * 64 + j * 16 + n16][(q4 ^ fn) * 8];
#pragma unroll
    for (int i = 0; i < 4; ++i)
#pragma unroll
      for (int j = 0; j < 4; ++j)
        acc[i][j] = __builtin_amdgcn_mfma_f32_16x16x32_bf16(af[i], bfr[j], acc[i][j], 0, 0, 0);
  }

  float rsum[4][4];
#pragma unroll
  for (int i = 0; i < 4; ++i)
#pragma unroll
    for (int r = 0; r < 4; ++r) rsum[i][r] = 0.f;
#pragma unroll
  for (int j = 0; j < 4; ++j) {
    const int col = c0 + wn * 64 + j * 16 + n16;
    const float qv = qp[bq * H_ + col];
    const float vv = Va_w[col];
#pragma unroll
    for (int i = 0; i < 4; ++i)
#pragma unroll
      for (int r = 0; r < 4; ++r)
        rsum[i][r] += fast_tanh(acc[i][j][r] + qv) * vv;
  }
#pragma unroll
  for (int i = 0; i < 4; ++i)
#pragma unroll
    for (int r = 0; r < 4; ++r) {
      float v = rsum[i][r];
      v += __shfl_xor(v, 1);
      v += __shfl_xor(v, 2);
      v += __shfl_xor(v, 4);
      v += __shfl_xor(v, 8);
      rsum[i][r] = v;
    }
  if (n16 == 0) {
#pragma unroll
    for (int i = 0; i < 4; ++i)
#pragma unroll
      for (int r = 0; r < 4; ++r)
        red[wn][wm * 64 + i * 16 + q4 * 4 + r] = rsum[i][r];
  }
  __syncthreads();
  if (tid < 128) sp[(size_t)cb * M_ + row0 + tid] = red[0][tid] + red[1][tid];
}

// ---------------- fallback scores (fp32 sources, in-kernel convert) ----------------
__global__ __launch_bounds__(256) void scores_f32_kernel(
    const float* __restrict__ keys, const float* __restrict__ Ua_w,
    const float* __restrict__ qp, const float* __restrict__ Va_w,
    float* __restrict__ sp) {
  const int tid = threadIdx.x;
  int rb, cb;
  swizzle_rc(blockIdx.x, rb, cb);
  const int row0 = rb * 128, c0 = cb * 128;
  const int bq = row0 >> 11;
  const int lane = tid & 63;
  const int w = tid >> 6;
  const int wm = w >> 1, wn = w & 1;
  const int q4 = lane >> 4, n16 = lane & 15;

  __shared__ __align__(16) unsigned short Asm[128][40];
  __shared__ __align__(16) unsigned short Bsm[128][40];
  __shared__ float red[2][128];

  floatx4 acc[4][4];
#pragma unroll
  for (int i = 0; i < 4; ++i)
#pragma unroll
    for (int j = 0; j < 4; ++j) acc[i][j] = {0.f, 0.f, 0.f, 0.f};

  for (int kt = 0; kt < 32; ++kt) {
    const int k0 = kt * 32;
    __syncthreads();
#pragma unroll
    for (int rep = 0; rep < 4; ++rep) {
      const int idx4 = rep * 256 + tid;
      const int r = idx4 >> 3;
      const int c4 = (idx4 & 7) << 2;
      const float4 va = *(const float4*)(keys + (size_t)(row0 + r) * H_ + k0 + c4);
      *(uint2*)&Asm[r][c4] = make_uint2(pk2(va.x, va.y), pk2(va.z, va.w));
      const float4 vb = *(const float4*)(Ua_w + (size_t)(c0 + r) * H_ + k0 + c4);
      *(uint2*)&Bsm[r][c4] = make_uint2(pk2(vb.x, vb.y), pk2(vb.z, vb.w));
    }
    __syncthreads();
    bf16x8 af[4], bfr[4];
#pragma unroll
    for (int i = 0; i < 4; ++i)
      af[i] = *(const bf16x8*)&Asm[wm * 64 + i * 16 + n16][q4 * 8];
#pragma unroll
    for (int j = 0; j < 4; ++j)
      bfr[j] = *(const bf16x8*)&Bsm[wn * 64 + j * 16 + n16][q4 * 8];
#pragma unroll
    for (int i = 0; i < 4; ++i)
#pragma unroll
      for (int j = 0; j < 4; ++j)
        acc[i][j] = __builtin_amdgcn_mfma_f32_16x16x32_bf16(af[i], bfr[j], acc[i][j], 0, 0, 0);
  }

  float rsum[4][4];
#pragma unroll
  for (int i = 0; i < 4; ++i)
#pragma unroll
    for (int r = 0; r < 4; ++r) rsum[i][r] = 0.f;
#pragma unroll
  for (int j = 0; j < 4; ++j) {
    const int col = c0 + wn * 64 + j * 16 + n16;
    const float qv = qp[bq * H_ + col];
    const float vv = Va_w[col];
#pragma unroll
    for (int i = 0; i < 4; ++i)
#pragma unroll
      for (int r = 0; r < 4; ++r)
        rsum[i][r] += fast_tanh(acc[i][j][r] + qv) * vv;
  }
#pragma unroll
  for (int i = 0; i < 4; ++i)
#pragma unroll
    for (int r = 0; r < 4; ++r) {
      float v = rsum[i][r];
      v += __shfl_xor(v, 1);
      v += __shfl_xor(v, 2);
      v += __shfl_xor(v, 4);
      v += __shfl_xor(v, 8);
      rsum[i][r] = v;
    }
  if (n16 == 0) {
#pragma unroll
    for (int i = 0; i < 4; ++i)
#pragma unroll
      for (int r = 0; r < 4; ++r)
        red[wn][wm * 64 + i * 16 + q4 * 4 + r] = rsum[i][r];
  }
  __syncthreads();
  if (tid < 128) sp[(size_t)cb * M_ + row0 + tid] = red[0][tid] + red[1][tid];
}

// ---------------- softmax: sum 8 partials, softmax over S, write weights ----------------
__global__ __launch_bounds__(256) void softmax_kernel(
    const float* __restrict__ sp, float* __restrict__ sw) {
  const int b = blockIdx.x, tid = threadIdx.x;
  float v[8];
#pragma unroll
  for (int k = 0; k < 8; ++k) {
    const size_t base = (size_t)b * S_ + tid + 256 * k;
    float s = 0.f;
#pragma unroll
    for (int j = 0; j < 8; ++j) s += sp[(size_t)j * M_ + base];
    v[k] = s;
  }
  float mx = v[0];
#pragma unroll
  for (int k = 1; k < 8; ++k) mx = fmaxf(mx, v[k]);
#pragma unroll
  for (int m = 32; m; m >>= 1) mx = fmaxf(mx, __shfl_xor(mx, m));
  __shared__ float sred[4], ssum[4];
  if ((tid & 63) == 0) sred[tid >> 6] = mx;
  __syncthreads();
  mx = fmaxf(fmaxf(sred[0], sred[1]), fmaxf(sred[2], sred[3]));
  float e[8], s = 0.f;
#pragma unroll
  for (int k = 0; k < 8; ++k) { e[k] = __expf(v[k] - mx); s += e[k]; }
#pragma unroll
  for (int m = 32; m; m >>= 1) s += __shfl_xor(s, m);
  if ((tid & 63) == 0) ssum[tid >> 6] = s;
  __syncthreads();
  s = ssum[0] + ssum[1] + ssum[2] + ssum[3];
  const float inv = 1.0f / s;
#pragma unroll
  for (int k = 0; k < 8; ++k) sw[b * S_ + tid + 256 * k] = e[k] * inv;
}

// ---------------- context stage 1: (b, 32-s chunk) partials, register-blocked ----------------
__global__ __launch_bounds__(256) void context1_kernel(
    const float* __restrict__ keys, const float* __restrict__ weights,
    float* __restrict__ pctx) {
  const int b = blockIdx.x >> 6;
  const int ch = blockIdx.x & 63;
  const int s0 = ch * 32;
  const int h4 = threadIdx.x;  // float4 index
  const float4* kp4 = (const float4*)(keys + (size_t)(b * S_ + s0) * H_) + h4;
  const float4* wp4 = (const float4*)(weights + b * S_ + s0);
  float4 acc = {0.f, 0.f, 0.f, 0.f};
#pragma unroll
  for (int sq = 0; sq < 8; ++sq) {
    const float4 wv = wp4[sq];
    const float4 k0 = kp4[(sq * 4 + 0) * 256];
    const float4 k1 = kp4[(sq * 4 + 1) * 256];
    const float4 k2 = kp4[(sq * 4 + 2) * 256];
    const float4 k3 = kp4[(sq * 4 + 3) * 256];
    acc.x += wv.x * k0.x + wv.y * k1.x + wv.z * k2.x + wv.w * k3.x;
    acc.y += wv.x * k0.y + wv.y * k1.y + wv.z * k2.y + wv.w * k3.y;
    acc.z += wv.x * k0.z + wv.y * k1.z + wv.z * k2.z + wv.w * k3.z;
    acc.w += wv.x * k0.w + wv.y * k1.w + wv.z * k2.w + wv.w * k3.w;
  }
  *(float4*)(pctx + ((size_t)(b * 64 + ch)) * H_ + h4 * 4) = acc;
}

// ---------------- context stage 2: reduce 64 partials ----------------
__global__ __launch_bounds__(256) void context2_kernel(
    const float* __restrict__ pctx, float* __restrict__ ctx) {
  const int b = blockIdx.x;
  const int h4 = threadIdx.x * 4;
  float4 acc = {0.f, 0.f, 0.f, 0.f};
#pragma unroll 8
  for (int c = 0; c < 64; ++c) {
    const float4 v = *(const float4*)(pctx + ((size_t)(b * 64 + c)) * H_ + h4);
    acc.x += v.x; acc.y += v.y; acc.z += v.z; acc.w += v.w;
  }
  *(float4*)(ctx + b * H_ + h4) = acc;
}

extern "C" void kernel_launch(void* const* d_in, const int* in_sizes, int n_in,
                              void* d_out, int out_size, void* d_ws, size_t ws_size,
                              hipStream_t stream) {
  const float* query = (const float*)d_in[0];
  const float* keys  = (const float*)d_in[1];
  const float* Wa_w  = (const float*)d_in[2];
  const float* Wa_b  = (const float*)d_in[3];
  const float* Ua_w  = (const float*)d_in[4];
  const float* Ua_b  = (const float*)d_in[5];
  const float* Va_w  = (const float*)d_in[6];
  // d_in[7] = Va_b (softmax shift-invariant), d_in[8] = idx — unused.

  float* out = (float*)d_out;
  float* ctx = out;
  float* sw  = out + B_ * H_;

  // ws layout: qp 128K | sp 2M | pctx 8M | ubf 2M   (kbf eliminated)
  const size_t qpb = (size_t)B_ * H_ * 4;
  const size_t spb = (size_t)8 * M_ * 4;
  const size_t pcb = (size_t)B_ * 64 * H_ * 4;
  const size_t ub  = (size_t)H_ * H_ * 2;
  float* qp = (float*)d_ws;
  float* sp = (float*)((char*)d_ws + qpb);
  float* pctx = (float*)((char*)d_ws + qpb + spb);
  unsigned short* ubf = (unsigned short*)((char*)d_ws + qpb + spb + pcb);
  const bool fast = ws_size >= qpb + spb + pcb + ub;

  prep_kernel<<<QP_BLOCKS + UA_BLOCKS, 256, 0, stream>>>(
      Ua_w, query, Wa_w, Wa_b, Ua_b, ubf, qp, fast ? 1 : 0);
  if (fast) {
    scores_af32_kernel<<<4096, 256, 0, stream>>>(keys, ubf, qp, Va_w, sp);
  } else {
    scores_f32_kernel<<<4096, 256, 0, stream>>>(keys, Ua_w, qp, Va_w, sp);
  }
  softmax_kernel<<<B_, 256, 0, stream>>>(sp, sw);
  context1_kernel<<<2048, 256, 0, stream>>>(keys, sw, pctx);
  context2_kernel<<<B_, 256, 0, stream>>>(pctx, ctx);
}

// Round 2
// 693.247 us; speedup vs baseline: 1.0486x; 1.0486x over previous
//
#include <hip/hip_runtime.h>
#include <hip/hip_bf16.h>
#include <math.h>

// BahdanauAttention: B=32, S=2048, H=1024, fp32 in/out.
// R7: fused fp32-keys scores GEMM with LDS DOUBLE-BUFFERING (fixes R6's
// zero-distance prefetch: __syncthreads drains vmcnt(0), so loads must be
// issued a full compute phase before the barrier that needs them).
// Per K-step: issue A(kt+1)->regs + GLDS B(kt+1)->Bsm[1-cur] at top, compute
// buf[cur] (ds_read + 16 MFMA), cvt+ds_write A(kt+1)->Asm[1-cur], ONE barrier.
// keys fp32->bf16 conversion pass stays eliminated (saves ~105 us of HBM
// streaming measured via R5/R6 subtraction).
// B-operand (Ua, 2 MB bf16) keeps the proven GLDS width-16 path.

#define B_ 32
#define S_ 2048
#define H_ 1024
#define M_ (B_ * S_)

#define QP_BLOCKS 512      // qproj
#define UA_BLOCKS 32       // Ua fp32->bf16

typedef __bf16 bf16x8 __attribute__((ext_vector_type(8)));
typedef float floatx4 __attribute__((ext_vector_type(4)));

__device__ inline unsigned bf16_rne(float f) {
  unsigned u = __builtin_bit_cast(unsigned, f);
  return (u + 0x7fffu + ((u >> 16) & 1u)) >> 16;
}
__device__ inline unsigned pk2(float x, float y) {
  return bf16_rne(x) | (bf16_rne(y) << 16);
}
// HW packed f32->bf16 (RNE) — 1 op per 2 elements.
__device__ inline unsigned cvtpk(float x, float y) {
  unsigned r;
  asm("v_cvt_pk_bf16_f32 %0, %1, %2" : "=v"(r) : "v"(x), "v"(y));
  return r;
}

// tanh via v_exp_f32 + v_rcp_f32 (~7 ops); rel err ~1e-6, << bf16 GEMM noise.
__device__ inline float fast_tanh(float x) {
  const float xc = fminf(fmaxf(x, -8.f), 8.f);
  const float e = __expf(2.f * xc);
  return (e - 1.f) * __builtin_amdgcn_rcpf(e + 1.f);
}

#define GLDS(g, l)                                                    \
  __builtin_amdgcn_global_load_lds(                                   \
      (const __attribute__((address_space(1))) void*)(g),             \
      (__attribute__((address_space(3))) void*)(l), 16, 0, 0)

__device__ inline uint4 conv8(const float4* s2) {
  const float4 a = s2[0], b = s2[1];
  uint4 o;
  o.x = pk2(a.x, a.y); o.y = pk2(a.z, a.w);
  o.z = pk2(b.x, b.y); o.w = pk2(b.z, b.w);
  return o;
}

// ---------------- prep: qproj | Ua->bf16 ----------------
__global__ __launch_bounds__(256) void prep_kernel(
    const float* __restrict__ Ua_w, const float* __restrict__ query,
    const float* __restrict__ Wa_w, const float* __restrict__ Wa_b,
    const float* __restrict__ Ua_b, unsigned short* __restrict__ ubf,
    float* __restrict__ qp, int do_ua) {
  const int blk = blockIdx.x;
  const int tid = threadIdx.x;
  if (blk < QP_BLOCKS) {
    // qproj: block = (b, 64-o slice). Wa read 64 rows/block coalesced; query in LDS.
    const int b = blk >> 4;
    const int os = (blk & 15) * 64;
    const int lane = tid & 63;
    const int w = tid >> 6;
    __shared__ float qsh[H_];
    *(float4*)&qsh[tid * 4] = *(const float4*)(query + (size_t)b * H_ + tid * 4);
    __syncthreads();
    for (int t = 0; t < 16; ++t) {
      const int o = os + w * 16 + t;
      const float* wr = Wa_w + (size_t)o * H_;
      float p = 0.f;
#pragma unroll
      for (int j = 0; j < 16; ++j) p += wr[lane + 64 * j] * qsh[lane + 64 * j];
#pragma unroll
      for (int m = 32; m; m >>= 1) p += __shfl_xor(p, m);
      if (lane == 0) qp[b * H_ + o] = p + Wa_b[o] + Ua_b[o];
    }
  } else {
    if (!do_ua) return;
    const int tg = (blk - QP_BLOCKS) * 256 + tid;  // [0, 8192)
#pragma unroll
    for (int c = 0; c < 16; ++c) {
      const size_t idx = (size_t)c * 8192 + tg;  // < 131072
      ((uint4*)ubf)[idx] = conv8((const float4*)Ua_w + idx * 2);
    }
  }
}

// XCD swizzle: 8 colblocks of a rowblock share idx%8 -> same XCD L2 keys tile.
__device__ inline void swizzle_rc(int idx, int& rb, int& cb) {
  cb = (idx >> 3) & 7;
  rb = (idx & 7) | ((idx >> 6) << 3);
}
__device__ inline int chunk_f(int r) { return (r & 3) ^ ((r >> 2) & 3); }

// ---------------- scores: fp32-A double-buffered reg-staged + bf16 GEMM ----------------
__global__ __launch_bounds__(256) void scores_af32_kernel(
    const float* __restrict__ keys, const unsigned short* __restrict__ ubf,
    const float* __restrict__ qp, const float* __restrict__ Va_w,
    float* __restrict__ sp) {  // sp[cb][M_]
  const int tid = threadIdx.x;
  int rb, cb;
  swizzle_rc(blockIdx.x, rb, cb);
  const int row0 = rb * 128, c0 = cb * 128;
  const int bq = row0 >> 11;
  const int lane = tid & 63;
  const int w = tid >> 6;
  const int wm = w >> 1, wn = w & 1;
  const int q4 = lane >> 4, n16 = lane & 15;

  // Double-buffered tiles: [2][128][32] bf16 = 16 KB each.
  __shared__ __align__(16) unsigned short Asm[2][128][32];
  __shared__ __align__(16) unsigned short Bsm[2][128][32];
  __shared__ float red[2][128];
  const int BUFO = 128 * 32;  // shorts per buffer

  floatx4 acc[4][4];
#pragma unroll
  for (int i = 0; i < 4; ++i)
#pragma unroll
    for (int j = 0; j < 4; ++j) acc[i][j] = {0.f, 0.f, 0.f, 0.f};

  // B staging via GLDS (pre-swizzled global source).
  const int r0a = w * 32;
  const int lr = lane >> 2;
  const int lc = ((lane & 3) ^ chunk_f(lr)) * 8;
  const unsigned short* gB0 = ubf + (size_t)(c0 + r0a + lr) * H_ + lc;
  const unsigned short* gB1 = ubf + (size_t)(c0 + r0a + 16 + lr) * H_ + lc;
  unsigned short* lB0 = &Bsm[0][r0a][0];
  unsigned short* lB1 = &Bsm[0][r0a + 16][0];

  // A staging: thread t owns row ar = t>>1, global chunks ac0, ac0+1 (8 bf16 each).
  // LDS physical chunk = global chunk ^ chunk_f(row) — matches the ds_read side.
  const int ar = tid >> 1;
  const int ac0 = (tid & 1) * 2;
  const float* gA = keys + (size_t)(row0 + ar) * H_ + ac0 * 8;
  unsigned short* lA0 = &Asm[0][ar][((ac0 ^ chunk_f(ar)) & 3) * 8];
  unsigned short* lA1 = &Asm[0][ar][(((ac0 + 1) ^ chunk_f(ar)) & 3) * 8];

  const int fn = chunk_f(n16);

  // ---- Prologue: stage buf0 with K-step 0 ----
  float4 a0 = *(const float4*)(gA + 0);
  float4 a1 = *(const float4*)(gA + 4);
  float4 a2 = *(const float4*)(gA + 8);
  float4 a3 = *(const float4*)(gA + 12);
  GLDS(gB0, lB0);
  GLDS(gB1, lB1);
  {
    uint4 u0, u1;
    u0.x = cvtpk(a0.x, a0.y); u0.y = cvtpk(a0.z, a0.w);
    u0.z = cvtpk(a1.x, a1.y); u0.w = cvtpk(a1.z, a1.w);
    u1.x = cvtpk(a2.x, a2.y); u1.y = cvtpk(a2.z, a2.w);
    u1.z = cvtpk(a3.x, a3.y); u1.w = cvtpk(a3.z, a3.w);
    *(uint4*)lA0 = u0;
    *(uint4*)lA1 = u1;
  }
  __syncthreads();  // buf0 published (drains B(0) GLDS; zero overlap only once)

  for (int kt = 0; kt < 32; ++kt) {
    const int cur = kt & 1;
    const int nxt = cur ^ 1;
    // ---- Issue staging for kt+1 into buf[nxt] (its last readers were closed
    //      by the barrier ending iteration kt-1). ----
    if (kt < 31) {
      const int kn = (kt + 1) * 32;
      a0 = *(const float4*)(gA + kn + 0);
      a1 = *(const float4*)(gA + kn + 4);
      a2 = *(const float4*)(gA + kn + 8);
      a3 = *(const float4*)(gA + kn + 12);
      GLDS(gB0 + kn, lB0 + nxt * BUFO);
      GLDS(gB1 + kn, lB1 + nxt * BUFO);
    }
    __builtin_amdgcn_sched_barrier(0);  // pin load issue before compute phase
    // ---- Compute on buf[cur] ----
    bf16x8 af[4], bfr[4];
#pragma unroll
    for (int i = 0; i < 4; ++i)
      af[i] = *(const bf16x8*)(&Asm[0][wm * 64 + i * 16 + n16][(q4 ^ fn) * 8] + cur * BUFO);
#pragma unroll
    for (int j = 0; j < 4; ++j)
      bfr[j] = *(const bf16x8*)(&Bsm[0][wn * 64 + j * 16 + n16][(q4 ^ fn) * 8] + cur * BUFO);
#pragma unroll
    for (int i = 0; i < 4; ++i)
#pragma unroll
      for (int j = 0; j < 4; ++j)
        acc[i][j] = __builtin_amdgcn_mfma_f32_16x16x32_bf16(af[i], bfr[j], acc[i][j], 0, 0, 0);
    // ---- Convert+write A(kt+1); compiler inserts the vmcnt wait for a0..a3
    //      here, ~a full compute phase after issue. ----
    if (kt < 31) {
      uint4 u0, u1;
      u0.x = cvtpk(a0.x, a0.y); u0.y = cvtpk(a0.z, a0.w);
      u0.z = cvtpk(a1.x, a1.y); u0.w = cvtpk(a1.z, a1.w);
      u1.x = cvtpk(a2.x, a2.y); u1.y = cvtpk(a2.z, a2.w);
      u1.z = cvtpk(a3.x, a3.y); u1.w = cvtpk(a3.z, a3.w);
      *(uint4*)(lA0 + nxt * BUFO) = u0;
      *(uint4*)(lA1 + nxt * BUFO) = u1;
    }
    // One barrier per K-step: its vmcnt(0) drain only covers the B-GLDS issued
    // a full compute phase ago (and lgkmcnt(0) the ds_writes just above).
    __syncthreads();
  }

  float rsum[4][4];
#pragma unroll
  for (int i = 0; i < 4; ++i)
#pragma unroll
    for (int r = 0; r < 4; ++r) rsum[i][r] = 0.f;
#pragma unroll
  for (int j = 0; j < 4; ++j) {
    const int col = c0 + wn * 64 + j * 16 + n16;
    const float qv = qp[bq * H_ + col];
    const float vv = Va_w[col];
#pragma unroll
    for (int i = 0; i < 4; ++i)
#pragma unroll
      for (int r = 0; r < 4; ++r)
        rsum[i][r] += fast_tanh(acc[i][j][r] + qv) * vv;
  }
#pragma unroll
  for (int i = 0; i < 4; ++i)
#pragma unroll
    for (int r = 0; r < 4; ++r) {
      float v = rsum[i][r];
      v += __shfl_xor(v, 1);
      v += __shfl_xor(v, 2);
      v += __shfl_xor(v, 4);
      v += __shfl_xor(v, 8);
      rsum[i][r] = v;
    }
  if (n16 == 0) {
#pragma unroll
    for (int i = 0; i < 4; ++i)
#pragma unroll
      for (int r = 0; r < 4; ++r)
        red[wn][wm * 64 + i * 16 + q4 * 4 + r] = rsum[i][r];
  }
  __syncthreads();
  if (tid < 128) sp[(size_t)cb * M_ + row0 + tid] = red[0][tid] + red[1][tid];
}

// ---------------- fallback scores (fp32 sources, in-kernel convert) ----------------
__global__ __launch_bounds__(256) void scores_f32_kernel(
    const float* __restrict__ keys, const float* __restrict__ Ua_w,
    const float* __restrict__ qp, const float* __restrict__ Va_w,
    float* __restrict__ sp) {
  const int tid = threadIdx.x;
  int rb, cb;
  swizzle_rc(blockIdx.x, rb, cb);
  const int row0 = rb * 128, c0 = cb * 128;
  const int bq = row0 >> 11;
  const int lane = tid & 63;
  const int w = tid >> 6;
  const int wm = w >> 1, wn = w & 1;
  const int q4 = lane >> 4, n16 = lane & 15;

  __shared__ __align__(16) unsigned short Asm[128][40];
  __shared__ __align__(16) unsigned short Bsm[128][40];
  __shared__ float red[2][128];

  floatx4 acc[4][4];
#pragma unroll
  for (int i = 0; i < 4; ++i)
#pragma unroll
    for (int j = 0; j < 4; ++j) acc[i][j] = {0.f, 0.f, 0.f, 0.f};

  for (int kt = 0; kt < 32; ++kt) {
    const int k0 = kt * 32;
    __syncthreads();
#pragma unroll
    for (int rep = 0; rep < 4; ++rep) {
      const int idx4 = rep * 256 + tid;
      const int r = idx4 >> 3;
      const int c4 = (idx4 & 7) << 2;
      const float4 va = *(const float4*)(keys + (size_t)(row0 + r) * H_ + k0 + c4);
      *(uint2*)&Asm[r][c4] = make_uint2(pk2(va.x, va.y), pk2(va.z, va.w));
      const float4 vb = *(const float4*)(Ua_w + (size_t)(c0 + r) * H_ + k0 + c4);
      *(uint2*)&Bsm[r][c4] = make_uint2(pk2(vb.x, vb.y), pk2(vb.z, vb.w));
    }
    __syncthreads();
    bf16x8 af[4], bfr[4];
#pragma unroll
    for (int i = 0; i < 4; ++i)
      af[i] = *(const bf16x8*)&Asm[wm * 64 + i * 16 + n16][q4 * 8];
#pragma unroll
    for (int j = 0; j < 4; ++j)
      bfr[j] = *(const bf16x8*)&Bsm[wn * 64 + j * 16 + n16][q4 * 8];
#pragma unroll
    for (int i = 0; i < 4; ++i)
#pragma unroll
      for (int j = 0; j < 4; ++j)
        acc[i][j] = __builtin_amdgcn_mfma_f32_16x16x32_bf16(af[i], bfr[j], acc[i][j], 0, 0, 0);
  }

  float rsum[4][4];
#pragma unroll
  for (int i = 0; i < 4; ++i)
#pragma unroll
    for (int r = 0; r < 4; ++r) rsum[i][r] = 0.f;
#pragma unroll
  for (int j = 0; j < 4; ++j) {
    const int col = c0 + wn * 64 + j * 16 + n16;
    const float qv = qp[bq * H_ + col];
    const float vv = Va_w[col];
#pragma unroll
    for (int i = 0; i < 4; ++i)
#pragma unroll
      for (int r = 0; r < 4; ++r)
        rsum[i][r] += fast_tanh(acc[i][j][r] + qv) * vv;
  }
#pragma unroll
  for (int i = 0; i < 4; ++i)
#pragma unroll
    for (int r = 0; r < 4; ++r) {
      float v = rsum[i][r];
      v += __shfl_xor(v, 1);
      v += __shfl_xor(v, 2);
      v += __shfl_xor(v, 4);
      v += __shfl_xor(v, 8);
      rsum[i][r] = v;
    }
  if (n16 == 0) {
#pragma unroll
    for (int i = 0; i < 4; ++i)
#pragma unroll
      for (int r = 0; r < 4; ++r)
        red[wn][wm * 64 + i * 16 + q4 * 4 + r] = rsum[i][r];
  }
  __syncthreads();
  if (tid < 128) sp[(size_t)cb * M_ + row0 + tid] = red[0][tid] + red[1][tid];
}

// ---------------- softmax: sum 8 partials, softmax over S, write weights ----------------
__global__ __launch_bounds__(256) void softmax_kernel(
    const float* __restrict__ sp, float* __restrict__ sw) {
  const int b = blockIdx.x, tid = threadIdx.x;
  float v[8];
#pragma unroll
  for (int k = 0; k < 8; ++k) {
    const size_t base = (size_t)b * S_ + tid + 256 * k;
    float s = 0.f;
#pragma unroll
    for (int j = 0; j < 8; ++j) s += sp[(size_t)j * M_ + base];
    v[k] = s;
  }
  float mx = v[0];
#pragma unroll
  for (int k = 1; k < 8; ++k) mx = fmaxf(mx, v[k]);
#pragma unroll
  for (int m = 32; m; m >>= 1) mx = fmaxf(mx, __shfl_xor(mx, m));
  __shared__ float sred[4], ssum[4];
  if ((tid & 63) == 0) sred[tid >> 6] = mx;
  __syncthreads();
  mx = fmaxf(fmaxf(sred[0], sred[1]), fmaxf(sred[2], sred[3]));
  float e[8], s = 0.f;
#pragma unroll
  for (int k = 0; k < 8; ++k) { e[k] = __expf(v[k] - mx); s += e[k]; }
#pragma unroll
  for (int m = 32; m; m >>= 1) s += __shfl_xor(s, m);
  if ((tid & 63) == 0) ssum[tid >> 6] = s;
  __syncthreads();
  s = ssum[0] + ssum[1] + ssum[2] + ssum[3];
  const float inv = 1.0f / s;
#pragma unroll
  for (int k = 0; k < 8; ++k) sw[b * S_ + tid + 256 * k] = e[k] * inv;
}

// ---------------- context stage 1: (b, 32-s chunk) partials, register-blocked ----------------
__global__ __launch_bounds__(256) void context1_kernel(
    const float* __restrict__ keys, const float* __restrict__ weights,
    float* __restrict__ pctx) {
  const int b = blockIdx.x >> 6;
  const int ch = blockIdx.x & 63;
  const int s0 = ch * 32;
  const int h4 = threadIdx.x;  // float4 index
  const float4* kp4 = (const float4*)(keys + (size_t)(b * S_ + s0) * H_) + h4;
  const float4* wp4 = (const float4*)(weights + b * S_ + s0);
  float4 acc = {0.f, 0.f, 0.f, 0.f};
#pragma unroll
  for (int sq = 0; sq < 8; ++sq) {
    const float4 wv = wp4[sq];
    const float4 k0 = kp4[(sq * 4 + 0) * 256];
    const float4 k1 = kp4[(sq * 4 + 1) * 256];
    const float4 k2 = kp4[(sq * 4 + 2) * 256];
    const float4 k3 = kp4[(sq * 4 + 3) * 256];
    acc.x += wv.x * k0.x + wv.y * k1.x + wv.z * k2.x + wv.w * k3.x;
    acc.y += wv.x * k0.y + wv.y * k1.y + wv.z * k2.y + wv.w * k3.y;
    acc.z += wv.x * k0.z + wv.y * k1.z + wv.z * k2.z + wv.w * k3.z;
    acc.w += wv.x * k0.w + wv.y * k1.w + wv.z * k2.w + wv.w * k3.w;
  }
  *(float4*)(pctx + ((size_t)(b * 64 + ch)) * H_ + h4 * 4) = acc;
}

// ---------------- context stage 2: reduce 64 partials ----------------
__global__ __launch_bounds__(256) void context2_kernel(
    const float* __restrict__ pctx, float* __restrict__ ctx) {
  const int b = blockIdx.x;
  const int h4 = threadIdx.x * 4;
  float4 acc = {0.f, 0.f, 0.f, 0.f};
#pragma unroll 8
  for (int c = 0; c < 64; ++c) {
    const float4 v = *(const float4*)(pctx + ((size_t)(b * 64 + c)) * H_ + h4);
    acc.x += v.x; acc.y += v.y; acc.z += v.z; acc.w += v.w;
  }
  *(float4*)(ctx + b * H_ + h4) = acc;
}

extern "C" void kernel_launch(void* const* d_in, const int* in_sizes, int n_in,
                              void* d_out, int out_size, void* d_ws, size_t ws_size,
                              hipStream_t stream) {
  const float* query = (const float*)d_in[0];
  const float* keys  = (const float*)d_in[1];
  const float* Wa_w  = (const float*)d_in[2];
  const float* Wa_b  = (const float*)d_in[3];
  const float* Ua_w  = (const float*)d_in[4];
  const float* Ua_b  = (const float*)d_in[5];
  const float* Va_w  = (const float*)d_in[6];
  // d_in[7] = Va_b (softmax shift-invariant), d_in[8] = idx — unused.

  float* out = (float*)d_out;
  float* ctx = out;
  float* sw  = out + B_ * H_;

  // ws layout: qp 128K | sp 2M | pctx 8M | ubf 2M
  const size_t qpb = (size_t)B_ * H_ * 4;
  const size_t spb = (size_t)8 * M_ * 4;
  const size_t pcb = (size_t)B_ * 64 * H_ * 4;
  const size_t ub  = (size_t)H_ * H_ * 2;
  float* qp = (float*)d_ws;
  float* sp = (float*)((char*)d_ws + qpb);
  float* pctx = (float*)((char*)d_ws + qpb + spb);
  unsigned short* ubf = (unsigned short*)((char*)d_ws + qpb + spb + pcb);
  const bool fast = ws_size >= qpb + spb + pcb + ub;

  prep_kernel<<<QP_BLOCKS + UA_BLOCKS, 256, 0, stream>>>(
      Ua_w, query, Wa_w, Wa_b, Ua_b, ubf, qp, fast ? 1 : 0);
  if (fast) {
    scores_af32_kernel<<<4096, 256, 0, stream>>>(keys, ubf, qp, Va_w, sp);
  } else {
    scores_f32_kernel<<<4096, 256, 0, stream>>>(keys, Ua_w, qp, Va_w, sp);
  }
  softmax_kernel<<<B_, 256, 0, stream>>>(sp, sw);
  context1_kernel<<<2048, 256, 0, stream>>>(keys, sw, pctx);
  context2_kernel<<<B_, 256, 0, stream>>>(pctx, ctx);
}

// Round 4
// 640.003 us; speedup vs baseline: 1.1358x; 1.0832x over previous
//
#include <hip/hip_runtime.h>
#include <hip/hip_bf16.h>
#include <math.h>

// BahdanauAttention: B=32, S=2048, H=1024, fp32 in/out.
// R8 (resubmit — prior run died to container infra, not the kernel):
// scores GEMM back to the PROVEN R5 single-buffer 2-barrier GLDS structure;
// A (keys) staged as fp32 via GLDS (no conversion pass, no VGPR round-trip),
// converted to bf16 on the READ side (cvt_pk between ds_read and MFMA).
// fp32 A rows are 128 B; bank conflicts handled by pre-swizzling the GLOBAL
// source chunk (l&7)^(l>>3) with linear LDS dest (GLDS constraint), read side
// XORs chunk with row&7. B (Ua bf16) path byte-identical to R5.
// R6/R7 lesson: VGPR-staged A puts data waits + cvt + ds_write on the
// critical path and halves occupancy -> MfmaUtil 15%; GLDS avoids all three.

#define B_ 32
#define S_ 2048
#define H_ 1024
#define M_ (B_ * S_)

#define QP_BLOCKS 512      // qproj
#define UA_BLOCKS 32       // Ua fp32->bf16

typedef __bf16 bf16x8 __attribute__((ext_vector_type(8)));
typedef float floatx4 __attribute__((ext_vector_type(4)));

__device__ inline unsigned bf16_rne(float f) {
  unsigned u = __builtin_bit_cast(unsigned, f);
  return (u + 0x7fffu + ((u >> 16) & 1u)) >> 16;
}
__device__ inline unsigned pk2(float x, float y) {
  return bf16_rne(x) | (bf16_rne(y) << 16);
}
// HW packed f32->bf16 (RNE) — 1 op per 2 elements, bit-identical to pk2.
__device__ inline unsigned cvtpk(float x, float y) {
  unsigned r;
  asm("v_cvt_pk_bf16_f32 %0, %1, %2" : "=v"(r) : "v"(x), "v"(y));
  return r;
}

// tanh via v_exp_f32 + v_rcp_f32 (~7 ops); rel err ~1e-6, << bf16 GEMM noise.
__device__ inline float fast_tanh(float x) {
  const float xc = fminf(fmaxf(x, -8.f), 8.f);
  const float e = __expf(2.f * xc);
  return (e - 1.f) * __builtin_amdgcn_rcpf(e + 1.f);
}

#define GLDS(g, l)                                                    \
  __builtin_amdgcn_global_load_lds(                                   \
      (const __attribute__((address_space(1))) void*)(g),             \
      (__attribute__((address_space(3))) void*)(l), 16, 0, 0)

__device__ inline uint4 conv8(const float4* s2) {
  const float4 a = s2[0], b = s2[1];
  uint4 o;
  o.x = pk2(a.x, a.y); o.y = pk2(a.z, a.w);
  o.z = pk2(b.x, b.y); o.w = pk2(b.z, b.w);
  return o;
}

// ---------------- prep: qproj | Ua->bf16 ----------------
__global__ __launch_bounds__(256) void prep_kernel(
    const float* __restrict__ Ua_w, const float* __restrict__ query,
    const float* __restrict__ Wa_w, const float* __restrict__ Wa_b,
    const float* __restrict__ Ua_b, unsigned short* __restrict__ ubf,
    float* __restrict__ qp, int do_ua) {
  const int blk = blockIdx.x;
  const int tid = threadIdx.x;
  if (blk < QP_BLOCKS) {
    // qproj: block = (b, 64-o slice). Wa read 64 rows/block coalesced; query in LDS.
    const int b = blk >> 4;
    const int os = (blk & 15) * 64;
    const int lane = tid & 63;
    const int w = tid >> 6;
    __shared__ float qsh[H_];
    *(float4*)&qsh[tid * 4] = *(const float4*)(query + (size_t)b * H_ + tid * 4);
    __syncthreads();
    for (int t = 0; t < 16; ++t) {
      const int o = os + w * 16 + t;
      const float* wr = Wa_w + (size_t)o * H_;
      float p = 0.f;
#pragma unroll
      for (int j = 0; j < 16; ++j) p += wr[lane + 64 * j] * qsh[lane + 64 * j];
#pragma unroll
      for (int m = 32; m; m >>= 1) p += __shfl_xor(p, m);
      if (lane == 0) qp[b * H_ + o] = p + Wa_b[o] + Ua_b[o];
    }
  } else {
    if (!do_ua) return;
    const int tg = (blk - QP_BLOCKS) * 256 + tid;  // [0, 8192)
#pragma unroll
    for (int c = 0; c < 16; ++c) {
      const size_t idx = (size_t)c * 8192 + tg;  // < 131072
      ((uint4*)ubf)[idx] = conv8((const float4*)Ua_w + idx * 2);
    }
  }
}

// XCD swizzle: 8 colblocks of a rowblock share idx%8 -> same XCD L2 keys tile.
__device__ inline void swizzle_rc(int idx, int& rb, int& cb) {
  cb = (idx >> 3) & 7;
  rb = (idx & 7) | ((idx >> 6) << 3);
}
__device__ inline int chunk_f(int r) { return (r & 3) ^ ((r >> 2) & 3); }

// ---------------- scores: fp32-A GLDS + read-side cvt + bf16 GEMM ----------------
__global__ __launch_bounds__(256) void scores_af32_kernel(
    const float* __restrict__ keys, const unsigned short* __restrict__ ubf,
    const float* __restrict__ qp, const float* __restrict__ Va_w,
    float* __restrict__ sp) {  // sp[cb][M_]
  const int tid = threadIdx.x;
  int rb, cb;
  swizzle_rc(blockIdx.x, rb, cb);
  const int row0 = rb * 128, c0 = cb * 128;
  const int bq = row0 >> 11;
  const int lane = tid & 63;
  const int w = tid >> 6;
  const int wm = w >> 1, wn = w & 1;
  const int q4 = lane >> 4, n16 = lane & 15;

  __shared__ __align__(16) float Asmf[128][32];          // fp32 A tile, 16 KB
  __shared__ __align__(16) unsigned short Bsm[128][32];  // bf16 B tile, 8 KB
  __shared__ float red[2][128];

  floatx4 acc[4][4];
#pragma unroll
  for (int i = 0; i < 4; ++i)
#pragma unroll
    for (int j = 0; j < 4; ++j) acc[i][j] = {0.f, 0.f, 0.f, 0.f};

  const int r0a = w * 32;

  // B staging via GLDS (pre-swizzled global source), unchanged from R5.
  const int lr = lane >> 2;
  const int lc = ((lane & 3) ^ chunk_f(lr)) * 8;
  const unsigned short* gB0 = ubf + (size_t)(c0 + r0a + lr) * H_ + lc;
  const unsigned short* gB1 = ubf + (size_t)(c0 + r0a + 16 + lr) * H_ + lc;
  unsigned short* lB0 = &Bsm[r0a][0];
  unsigned short* lB1 = &Bsm[r0a + 16][0];

  // A staging (fp32): 4 GLDS/wave, instr i covers rows r0a+8i..+7.
  // lane l -> row r0a+8i+(l>>3); global 16B chunk (l&7)^(l>>3); LDS linear.
  // Read side XORs chunk with row&7 (= l>>3 here since r0a+8i ≡ 0 mod 8).
  const int arow = lane >> 3;                 // 0..7
  const int achk = ((lane & 7) ^ arow) * 4;   // float offset of swizzled chunk
  const float* gA0 = keys + (size_t)(row0 + r0a + 0 + arow) * H_ + achk;
  const float* gA1 = keys + (size_t)(row0 + r0a + 8 + arow) * H_ + achk;
  const float* gA2 = keys + (size_t)(row0 + r0a + 16 + arow) * H_ + achk;
  const float* gA3 = keys + (size_t)(row0 + r0a + 24 + arow) * H_ + achk;
  float* lA0 = &Asmf[r0a + 0][0];
  float* lA1 = &Asmf[r0a + 8][0];
  float* lA2 = &Asmf[r0a + 16][0];
  float* lA3 = &Asmf[r0a + 24][0];

  const int fn = chunk_f(n16);
  const int fa = n16 & 7;
  const int ac0f = (((q4 << 1) ^ fa)) << 2;        // float offset, chunk q4*2
  const int ac1f = (((q4 << 1) | 1) ^ fa) << 2;    // float offset, chunk q4*2+1

  for (int kt = 0; kt < 32; ++kt) {
    const int k0 = kt * 32;
    __syncthreads();
    GLDS(gA0 + k0, lA0);
    GLDS(gA1 + k0, lA1);
    GLDS(gA2 + k0, lA2);
    GLDS(gA3 + k0, lA3);
    GLDS(gB0 + k0, lB0);
    GLDS(gB1 + k0, lB1);
    __syncthreads();
    bf16x8 af[4], bfr[4];
#pragma unroll
    for (int i = 0; i < 4; ++i) {
      const float* ar = &Asmf[wm * 64 + i * 16 + n16][0];
      const float4 x0 = *(const float4*)(ar + ac0f);
      const float4 x1 = *(const float4*)(ar + ac1f);
      uint4 u;
      u.x = cvtpk(x0.x, x0.y); u.y = cvtpk(x0.z, x0.w);
      u.z = cvtpk(x1.x, x1.y); u.w = cvtpk(x1.z, x1.w);
      af[i] = __builtin_bit_cast(bf16x8, u);
    }
#pragma unroll
    for (int j = 0; j < 4; ++j)
      bfr[j] = *(const bf16x8*)&Bsm[wn * 64 + j * 16 + n16][(q4 ^ fn) * 8];
#pragma unroll
    for (int i = 0; i < 4; ++i)
#pragma unroll
      for (int j = 0; j < 4; ++j)
        acc[i][j] = __builtin_amdgcn_mfma_f32_16x16x32_bf16(af[i], bfr[j], acc[i][j], 0, 0, 0);
  }

  float rsum[4][4];
#pragma unroll
  for (int i = 0; i < 4; ++i)
#pragma unroll
    for (int r = 0; r < 4; ++r) rsum[i][r] = 0.f;
#pragma unroll
  for (int j = 0; j < 4; ++j) {
    const int col = c0 + wn * 64 + j * 16 + n16;
    const float qv = qp[bq * H_ + col];
    const float vv = Va_w[col];
#pragma unroll
    for (int i = 0; i < 4; ++i)
#pragma unroll
      for (int r = 0; r < 4; ++r)
        rsum[i][r] += fast_tanh(acc[i][j][r] + qv) * vv;
  }
#pragma unroll
  for (int i = 0; i < 4; ++i)
#pragma unroll
    for (int r = 0; r < 4; ++r) {
      float v = rsum[i][r];
      v += __shfl_xor(v, 1);
      v += __shfl_xor(v, 2);
      v += __shfl_xor(v, 4);
      v += __shfl_xor(v, 8);
      rsum[i][r] = v;
    }
  if (n16 == 0) {
#pragma unroll
    for (int i = 0; i < 4; ++i)
#pragma unroll
      for (int r = 0; r < 4; ++r)
        red[wn][wm * 64 + i * 16 + q4 * 4 + r] = rsum[i][r];
  }
  __syncthreads();
  if (tid < 128) sp[(size_t)cb * M_ + row0 + tid] = red[0][tid] + red[1][tid];
}

// ---------------- fallback scores (fp32 sources, in-kernel convert) ----------------
__global__ __launch_bounds__(256) void scores_f32_kernel(
    const float* __restrict__ keys, const float* __restrict__ Ua_w,
    const float* __restrict__ qp, const float* __restrict__ Va_w,
    float* __restrict__ sp) {
  const int tid = threadIdx.x;
  int rb, cb;
  swizzle_rc(blockIdx.x, rb, cb);
  const int row0 = rb * 128, c0 = cb * 128;
  const int bq = row0 >> 11;
  const int lane = tid & 63;
  const int w = tid >> 6;
  const int wm = w >> 1, wn = w & 1;
  const int q4 = lane >> 4, n16 = lane & 15;

  __shared__ __align__(16) unsigned short Asm[128][40];
  __shared__ __align__(16) unsigned short Bsm[128][40];
  __shared__ float red[2][128];

  floatx4 acc[4][4];
#pragma unroll
  for (int i = 0; i < 4; ++i)
#pragma unroll
    for (int j = 0; j < 4; ++j) acc[i][j] = {0.f, 0.f, 0.f, 0.f};

  for (int kt = 0; kt < 32; ++kt) {
    const int k0 = kt * 32;
    __syncthreads();
#pragma unroll
    for (int rep = 0; rep < 4; ++rep) {
      const int idx4 = rep * 256 + tid;
      const int r = idx4 >> 3;
      const int c4 = (idx4 & 7) << 2;
      const float4 va = *(const float4*)(keys + (size_t)(row0 + r) * H_ + k0 + c4);
      *(uint2*)&Asm[r][c4] = make_uint2(pk2(va.x, va.y), pk2(va.z, va.w));
      const float4 vb = *(const float4*)(Ua_w + (size_t)(c0 + r) * H_ + k0 + c4);
      *(uint2*)&Bsm[r][c4] = make_uint2(pk2(vb.x, vb.y), pk2(vb.z, vb.w));
    }
    __syncthreads();
    bf16x8 af[4], bfr[4];
#pragma unroll
    for (int i = 0; i < 4; ++i)
      af[i] = *(const bf16x8*)&Asm[wm * 64 + i * 16 + n16][q4 * 8];
#pragma unroll
    for (int j = 0; j < 4; ++j)
      bfr[j] = *(const bf16x8*)&Bsm[wn * 64 + j * 16 + n16][q4 * 8];
#pragma unroll
    for (int i = 0; i < 4; ++i)
#pragma unroll
      for (int j = 0; j < 4; ++j)
        acc[i][j] = __builtin_amdgcn_mfma_f32_16x16x32_bf16(af[i], bfr[j], acc[i][j], 0, 0, 0);
  }

  float rsum[4][4];
#pragma unroll
  for (int i = 0; i < 4; ++i)
#pragma unroll
    for (int r = 0; r < 4; ++r) rsum[i][r] = 0.f;
#pragma unroll
  for (int j = 0; j < 4; ++j) {
    const int col = c0 + wn * 64 + j * 16 + n16;
    const float qv = qp[bq * H_ + col];
    const float vv = Va_w[col];
#pragma unroll
    for (int i = 0; i < 4; ++i)
#pragma unroll
      for (int r = 0; r < 4; ++r)
        rsum[i][r] += fast_tanh(acc[i][j][r] + qv) * vv;
  }
#pragma unroll
  for (int i = 0; i < 4; ++i)
#pragma unroll
    for (int r = 0; r < 4; ++r) {
      float v = rsum[i][r];
      v += __shfl_xor(v, 1);
      v += __shfl_xor(v, 2);
      v += __shfl_xor(v, 4);
      v += __shfl_xor(v, 8);
      rsum[i][r] = v;
    }
  if (n16 == 0) {
#pragma unroll
    for (int i = 0; i < 4; ++i)
#pragma unroll
      for (int r = 0; r < 4; ++r)
        red[wn][wm * 64 + i * 16 + q4 * 4 + r] = rsum[i][r];
  }
  __syncthreads();
  if (tid < 128) sp[(size_t)cb * M_ + row0 + tid] = red[0][tid] + red[1][tid];
}

// ---------------- softmax: sum 8 partials, softmax over S, write weights ----------------
__global__ __launch_bounds__(256) void softmax_kernel(
    const float* __restrict__ sp, float* __restrict__ sw) {
  const int b = blockIdx.x, tid = threadIdx.x;
  float v[8];
#pragma unroll
  for (int k = 0; k < 8; ++k) {
    const size_t base = (size_t)b * S_ + tid + 256 * k;
    float s = 0.f;
#pragma unroll
    for (int j = 0; j < 8; ++j) s += sp[(size_t)j * M_ + base];
    v[k] = s;
  }
  float mx = v[0];
#pragma unroll
  for (int k = 1; k < 8; ++k) mx = fmaxf(mx, v[k]);
#pragma unroll
  for (int m = 32; m; m >>= 1) mx = fmaxf(mx, __shfl_xor(mx, m));
  __shared__ float sred[4], ssum[4];
  if ((tid & 63) == 0) sred[tid >> 6] = mx;
  __syncthreads();
  mx = fmaxf(fmaxf(sred[0], sred[1]), fmaxf(sred[2], sred[3]));
  float e[8], s = 0.f;
#pragma unroll
  for (int k = 0; k < 8; ++k) { e[k] = __expf(v[k] - mx); s += e[k]; }
#pragma unroll
  for (int m = 32; m; m >>= 1) s += __shfl_xor(s, m);
  if ((tid & 63) == 0) ssum[tid >> 6] = s;
  __syncthreads();
  s = ssum[0] + ssum[1] + ssum[2] + ssum[3];
  const float inv = 1.0f / s;
#pragma unroll
  for (int k = 0; k < 8; ++k) sw[b * S_ + tid + 256 * k] = e[k] * inv;
}

// ---------------- context stage 1: (b, 32-s chunk) partials, register-blocked ----------------
__global__ __launch_bounds__(256) void context1_kernel(
    const float* __restrict__ keys, const float* __restrict__ weights,
    float* __restrict__ pctx) {
  const int b = blockIdx.x >> 6;
  const int ch = blockIdx.x & 63;
  const int s0 = ch * 32;
  const int h4 = threadIdx.x;  // float4 index
  const float4* kp4 = (const float4*)(keys + (size_t)(b * S_ + s0) * H_) + h4;
  const float4* wp4 = (const float4*)(weights + b * S_ + s0);
  float4 acc = {0.f, 0.f, 0.f, 0.f};
#pragma unroll
  for (int sq = 0; sq < 8; ++sq) {
    const float4 wv = wp4[sq];
    const float4 k0 = kp4[(sq * 4 + 0) * 256];
    const float4 k1 = kp4[(sq * 4 + 1) * 256];
    const float4 k2 = kp4[(sq * 4 + 2) * 256];
    const float4 k3 = kp4[(sq * 4 + 3) * 256];
    acc.x += wv.x * k0.x + wv.y * k1.x + wv.z * k2.x + wv.w * k3.x;
    acc.y += wv.x * k0.y + wv.y * k1.y + wv.z * k2.y + wv.w * k3.y;
    acc.z += wv.x * k0.z + wv.y * k1.z + wv.z * k2.z + wv.w * k3.z;
    acc.w += wv.x * k0.w + wv.y * k1.w + wv.z * k2.w + wv.w * k3.w;
  }
  *(float4*)(pctx + ((size_t)(b * 64 + ch)) * H_ + h4 * 4) = acc;
}

// ---------------- context stage 2: reduce 64 partials ----------------
__global__ __launch_bounds__(256) void context2_kernel(
    const float* __restrict__ pctx, float* __restrict__ ctx) {
  const int b = blockIdx.x;
  const int h4 = threadIdx.x * 4;
  float4 acc = {0.f, 0.f, 0.f, 0.f};
#pragma unroll 8
  for (int c = 0; c < 64; ++c) {
    const float4 v = *(const float4*)(pctx + ((size_t)(b * 64 + c)) * H_ + h4);
    acc.x += v.x; acc.y += v.y; acc.z += v.z; acc.w += v.w;
  }
  *(float4*)(ctx + b * H_ + h4) = acc;
}

extern "C" void kernel_launch(void* const* d_in, const int* in_sizes, int n_in,
                              void* d_out, int out_size, void* d_ws, size_t ws_size,
                              hipStream_t stream) {
  const float* query = (const float*)d_in[0];
  const float* keys  = (const float*)d_in[1];
  const float* Wa_w  = (const float*)d_in[2];
  const float* Wa_b  = (const float*)d_in[3];
  const float* Ua_w  = (const float*)d_in[4];
  const float* Ua_b  = (const float*)d_in[5];
  const float* Va_w  = (const float*)d_in[6];
  // d_in[7] = Va_b (softmax shift-invariant), d_in[8] = idx — unused.

  float* out = (float*)d_out;
  float* ctx = out;
  float* sw  = out + B_ * H_;

  // ws layout: qp 128K | sp 2M | pctx 8M | ubf 2M
  const size_t qpb = (size_t)B_ * H_ * 4;
  const size_t spb = (size_t)8 * M_ * 4;
  const size_t pcb = (size_t)B_ * 64 * H_ * 4;
  const size_t ub  = (size_t)H_ * H_ * 2;
  float* qp = (float*)d_ws;
  float* sp = (float*)((char*)d_ws + qpb);
  float* pctx = (float*)((char*)d_ws + qpb + spb);
  unsigned short* ubf = (unsigned short*)((char*)d_ws + qpb + spb + pcb);
  const bool fast = ws_size >= qpb + spb + pcb + ub;

  prep_kernel<<<QP_BLOCKS + UA_BLOCKS, 256, 0, stream>>>(
      Ua_w, query, Wa_w, Wa_b, Ua_b, ubf, qp, fast ? 1 : 0);
  if (fast) {
    scores_af32_kernel<<<4096, 256, 0, stream>>>(keys, ubf, qp, Va_w, sp);
  } else {
    scores_f32_kernel<<<4096, 256, 0, stream>>>(keys, Ua_w, qp, Va_w, sp);
  }
  softmax_kernel<<<B_, 256, 0, stream>>>(sp, sw);
  context1_kernel<<<2048, 256, 0, stream>>>(keys, sw, pctx);
  context2_kernel<<<B_, 256, 0, stream>>>(pctx, ctx);
}